// Round 6
// baseline (209.848 us; speedup 1.0000x reference)
//
#include <hip/hip_runtime.h>
#include <hip/hip_bf16.h>
#include <cstdint>
#include <cstddef>

typedef __bf16 bf16x8 __attribute__((ext_vector_type(8)));
typedef float f32x4 __attribute__((ext_vector_type(4)));
typedef float f32x16 __attribute__((ext_vector_type(16)));
typedef uint32_t u32x4 __attribute__((ext_vector_type(4)));
typedef __hip_bfloat16 bf16h;

__device__ __forceinline__ unsigned short bf16bits(float f) {
  bf16h h = __float2bfloat16(f);
  return __builtin_bit_cast(unsigned short, h);
}
__device__ __forceinline__ float bf16tof(unsigned short u) {
  union { uint32_t i; float f; } v; v.i = (uint32_t)u << 16; return v.f;
}

// ---------------- cast hidden fp32 -> bf16 ----------------
__global__ void cast_f32_bf16(const float* __restrict__ src, bf16h* __restrict__ dst, int n) {
  int i = (blockIdx.x * blockDim.x + threadIdx.x) * 4;
  if (i >= n) return;
  float4 v = *reinterpret_cast<const float4*>(src + i);
  ushort4 o;
  o.x = bf16bits(v.x); o.y = bf16bits(v.y); o.z = bf16bits(v.z); o.w = bf16bits(v.w);
  *reinterpret_cast<ushort4*>(dst + i) = o;
}

// ---------- transpose+cast+scale: src f32 [R][C] -> dst bf16 [C][R] ----------
__global__ void transpose_cast_f32(const float* __restrict__ src, bf16h* __restrict__ dst,
                                   int R, int C, float scale) {
  __shared__ float tile[32][33];
  int c0 = blockIdx.x * 32, r0 = blockIdx.y * 32;
  int tx = threadIdx.x, ty = threadIdx.y;
  #pragma unroll
  for (int i = 0; i < 32; i += 8)
    tile[ty + i][tx] = src[(size_t)(r0 + ty + i) * C + c0 + tx];
  __syncthreads();
  #pragma unroll
  for (int i = 0; i < 32; i += 8)
    dst[(size_t)(c0 + ty + i) * R + r0 + tx] = __float2bfloat16(tile[tx][ty + i] * scale);
}

__global__ void concat_bias(const float* __restrict__ bq, const float* __restrict__ bk,
                            const float* __restrict__ bv, float* __restrict__ bcat, float qscale) {
  int i = blockIdx.x * blockDim.x + threadIdx.x;
  if (i >= 2048) return;
  bcat[i] = (i < 1024) ? bq[i] * qscale : (i < 1536 ? bk[i - 1024] : bv[i - 1536]);
}

// ---------------- bf16 GEMM: C[M][N] = A[M][K] * BT[N][K]^T + bias ----------------
// Blocks with n0 >= vcol0 write TRANSPOSED into vtg[(col-vcol0)][row] (ld 4096) instead of C.
__device__ __forceinline__ void store_out(float* p, float v) { *p = v; }
__device__ __forceinline__ void store_out(bf16h* p, float v) { *p = __float2bfloat16(v); }

template <typename OutT>
__global__ __launch_bounds__(256) void gemm_bt(const bf16h* __restrict__ A, const bf16h* __restrict__ BT,
                                               const float* __restrict__ bias, OutT* __restrict__ C,
                                               int ldc, bf16h* __restrict__ vtg, int vcol0,
                                               int M, int N, int K) {
  __shared__ __align__(16) bf16h As[128 * 64];
  __shared__ __align__(16) bf16h Bs[128 * 64];
  const int tid = threadIdx.x;
  const int lane = tid & 63;
  const int m0 = blockIdx.y * 128, n0 = blockIdx.x * 128;
  const int wid = tid >> 6, wr = wid >> 1, wc = wid & 1;
  const int cl = lane & 15, rg = lane >> 4;
  const int srow = tid >> 3, scol = (tid & 7) * 8;
  f32x4 acc[4][4] = {};

  for (int k0 = 0; k0 < K; k0 += 64) {
    __syncthreads();
    #pragma unroll
    for (int i = 0; i < 4; ++i) {
      int r = i * 32 + srow;
      __builtin_amdgcn_global_load_lds(
          (__attribute__((address_space(1))) void*)(A + (size_t)(m0 + r) * K + k0 + scol),
          (__attribute__((address_space(3))) void*)(As + i * 2048 + tid * 8), 16, 0, 0);
    }
    #pragma unroll
    for (int i = 0; i < 4; ++i) {
      int r = i * 32 + srow;
      __builtin_amdgcn_global_load_lds(
          (__attribute__((address_space(1))) void*)(BT + (size_t)(n0 + r) * K + k0 + scol),
          (__attribute__((address_space(3))) void*)(Bs + i * 2048 + tid * 8), 16, 0, 0);
    }
    __syncthreads();
    #pragma unroll
    for (int ks = 0; ks < 2; ++ks) {
      bf16x8 af[4], bfr[4];
      #pragma unroll
      for (int mi = 0; mi < 4; ++mi)
        af[mi] = *reinterpret_cast<const bf16x8*>(As + (wr * 64 + mi * 16 + cl) * 64 + ks * 32 + rg * 8);
      #pragma unroll
      for (int ni = 0; ni < 4; ++ni)
        bfr[ni] = *reinterpret_cast<const bf16x8*>(Bs + (wc * 64 + ni * 16 + cl) * 64 + ks * 32 + rg * 8);
      #pragma unroll
      for (int mi = 0; mi < 4; ++mi)
        #pragma unroll
        for (int ni = 0; ni < 4; ++ni)
          acc[mi][ni] = __builtin_amdgcn_mfma_f32_16x16x32_bf16(af[mi], bfr[ni], acc[mi][ni], 0, 0, 0);
    }
  }
  if (n0 >= vcol0) {
    // transposed V^T store: vtg[col - vcol0][row], 4 consecutive rows per store
    #pragma unroll
    for (int ni = 0; ni < 4; ++ni) {
      int col = n0 + wc * 64 + ni * 16 + cl;
      float bv = bias[col];
      #pragma unroll
      for (int mi = 0; mi < 4; ++mi) {
        int row0 = m0 + wr * 64 + mi * 16 + rg * 4;
        ushort4 o;
        o.x = bf16bits(acc[mi][ni][0] + bv);
        o.y = bf16bits(acc[mi][ni][1] + bv);
        o.z = bf16bits(acc[mi][ni][2] + bv);
        o.w = bf16bits(acc[mi][ni][3] + bv);
        *reinterpret_cast<ushort4*>(vtg + (size_t)(col - vcol0) * 4096 + row0) = o;
      }
    }
  } else {
    #pragma unroll
    for (int ni = 0; ni < 4; ++ni) {
      int col = n0 + wc * 64 + ni * 16 + cl;
      float bv = bias[col];
      #pragma unroll
      for (int mi = 0; mi < 4; ++mi) {
        #pragma unroll
        for (int j = 0; j < 4; ++j) {
          int row = m0 + wr * 64 + mi * 16 + rg * 4 + j;
          store_out(&C[(size_t)row * ldc + col], acc[mi][ni][j] + bv);
        }
      }
    }
  }
}

// ---------------- flash attention: barrier-free, LDS-free, direct L2/L1 fragment loads ----------------
// qk:  [4096][1536] bf16 (Q pre-scaled by 0.125*log2e at h*64 | K at 1024+g*64)
// vt:  [512][4096] bf16 (V^T)
// part:[2][4096][16][64] bf16 unnormalized O partials; lpart: [2][4096][16] f32 row-sums
// 4 waves/block (independent, no __syncthreads), 64 q-rows/wave; KVBLK=64; blockIdx.z chunk = 2048 k's.
// A-fragment of 32x32x16: lane holds row=l31, k-elements 8*hi..8*hi+7 (16B contiguous).
__global__ __launch_bounds__(256, 2) void attn_fwd(const bf16h* __restrict__ qk,
                                                   const bf16h* __restrict__ vt,
                                                   bf16h* __restrict__ part,
                                                   float* __restrict__ lpart) {
  const int tid = threadIdx.x, lane = tid & 63, wid = tid >> 6;
  const int l31 = lane & 31, hi = lane >> 5;
  const int h = blockIdx.y, g = h >> 1, c = blockIdx.z;
  const int q0 = blockIdx.x * 256 + wid * 64;   // frag A: q0..q0+31, frag B: q0+32..q0+63
  const int kbase = c * 2048;

  // Q fragments (B-operand of swapped QK)
  bf16x8 qfA[4], qfB[4];
  {
    const bf16h* qrowA = qk + (size_t)(q0 + l31) * 1536 + h * 64 + hi * 8;
    const bf16h* qrowB = qrowA + (size_t)32 * 1536;
    #pragma unroll
    for (int ds = 0; ds < 4; ++ds) {
      qfA[ds] = *reinterpret_cast<const bf16x8*>(qrowA + ds * 16);
      qfB[ds] = *reinterpret_cast<const bf16x8*>(qrowB + ds * 16);
    }
  }

  // lane-fixed K/V base pointers: 8 elements (16B) per lane at k-offset 8*hi
  const bf16h* kp = qk + (size_t)(kbase + l31) * 1536 + 1024 + g * 64 + 8 * hi;
  const bf16h* vp = vt + (size_t)(g * 64 + l31) * 4096 + kbase + 8 * hi;

  f32x16 oA0, oA1, oB0, oB1;
  #pragma unroll
  for (int i = 0; i < 16; ++i) { oA0[i] = 0.f; oA1[i] = 0.f; oB0[i] = 0.f; oB1[i] = 0.f; }
  float lsumA = 0.f, lsumB = 0.f;

  // build P^T B-fragment from a k-slice of S (cvt_pk + permlane32_swap, T12)
  auto build_pa = [&](const f32x16& S, int u) -> bf16x8 {
    uint32_t w0, w1, w2, w3;
    asm("v_cvt_pk_bf16_f32 %0, %1, %2" : "=v"(w0) : "v"(S[8 * u + 0]), "v"(S[8 * u + 1]));
    asm("v_cvt_pk_bf16_f32 %0, %1, %2" : "=v"(w1) : "v"(S[8 * u + 2]), "v"(S[8 * u + 3]));
    asm("v_cvt_pk_bf16_f32 %0, %1, %2" : "=v"(w2) : "v"(S[8 * u + 4]), "v"(S[8 * u + 5]));
    asm("v_cvt_pk_bf16_f32 %0, %1, %2" : "=v"(w3) : "v"(S[8 * u + 6]), "v"(S[8 * u + 7]));
    asm("v_permlane32_swap_b32 %0, %1" : "+v"(w0), "+v"(w2));
    asm("v_permlane32_swap_b32 %0, %1" : "+v"(w1), "+v"(w3));
    u32x4 pw; pw[0] = w0; pw[1] = w1; pw[2] = w2; pw[3] = w3;
    return __builtin_bit_cast(bf16x8, pw);
  };

  for (int tt = 0; tt < 32; ++tt) {
    const bf16h* kt = kp + (size_t)(tt * 64) * 1536;
    const bf16h* vtp = vp + tt * 64;

    // ---- S^T = K * Q^T for both q-fragments (K fragments loaded direct from global)
    f32x16 sA0, sA1, sB0, sB1;
    #pragma unroll
    for (int i = 0; i < 16; ++i) { sA0[i] = 0.f; sA1[i] = 0.f; sB0[i] = 0.f; sB1[i] = 0.f; }
    __builtin_amdgcn_s_setprio(1);
    #pragma unroll
    for (int ds = 0; ds < 4; ++ds) {
      bf16x8 k0 = *reinterpret_cast<const bf16x8*>(kt + 16 * ds);
      bf16x8 k1 = *reinterpret_cast<const bf16x8*>(kt + (size_t)32 * 1536 + 16 * ds);
      sA0 = __builtin_amdgcn_mfma_f32_32x32x16_bf16(k0, qfA[ds], sA0, 0, 0, 0);
      sA1 = __builtin_amdgcn_mfma_f32_32x32x16_bf16(k1, qfA[ds], sA1, 0, 0, 0);
      sB0 = __builtin_amdgcn_mfma_f32_32x32x16_bf16(k0, qfB[ds], sB0, 0, 0, 0);
      sB1 = __builtin_amdgcn_mfma_f32_32x32x16_bf16(k1, qfB[ds], sB1, 0, 0, 0);
    }
    __builtin_amdgcn_s_setprio(0);

    // ---- issue V fragment loads now; latency hides under exp2/pack VALU
    bf16x8 vf[4][2];
    #pragma unroll
    for (int ks = 0; ks < 4; ++ks) {
      vf[ks][0] = *reinterpret_cast<const bf16x8*>(vtp + 16 * ks);
      vf[ks][1] = *reinterpret_cast<const bf16x8*>(vtp + (size_t)32 * 4096 + 16 * ks);
    }

    // ---- P = exp2(S) (fixed max; Q pre-scaled) + row-sums via 4 parallel accumulators
    float ra0 = 0.f, ra1 = 0.f, ra2 = 0.f, ra3 = 0.f;
    float rb0 = 0.f, rb1 = 0.f, rb2 = 0.f, rb3 = 0.f;
    #pragma unroll
    for (int r = 0; r < 16; r += 4) {
      #pragma unroll
      for (int j = 0; j < 4; ++j) {
        sA0[r + j] = __builtin_amdgcn_exp2f(sA0[r + j]);
        sA1[r + j] = __builtin_amdgcn_exp2f(sA1[r + j]);
        sB0[r + j] = __builtin_amdgcn_exp2f(sB0[r + j]);
        sB1[r + j] = __builtin_amdgcn_exp2f(sB1[r + j]);
      }
      ra0 += sA0[r] + sA0[r + 1]; ra1 += sA0[r + 2] + sA0[r + 3];
      ra2 += sA1[r] + sA1[r + 1]; ra3 += sA1[r + 2] + sA1[r + 3];
      rb0 += sB0[r] + sB0[r + 1]; rb1 += sB0[r + 2] + sB0[r + 3];
      rb2 += sB1[r] + sB1[r + 1]; rb3 += sB1[r + 2] + sB1[r + 3];
    }
    float rsA = (ra0 + ra1) + (ra2 + ra3);
    float rsB = (rb0 + rb1) + (rb2 + rb3);
    lsumA += rsA + __shfl_xor(rsA, 32);
    lsumB += rsB + __shfl_xor(rsB, 32);

    // ---- O^T += V^T P^T
    __builtin_amdgcn_s_setprio(1);
    #pragma unroll
    for (int ks = 0; ks < 4; ++ks) {
      const int u = ks & 1;
      bf16x8 paA = build_pa(ks < 2 ? sA0 : sA1, u);
      bf16x8 paB = build_pa(ks < 2 ? sB0 : sB1, u);
      oA0 = __builtin_amdgcn_mfma_f32_32x32x16_bf16(vf[ks][0], paA, oA0, 0, 0, 0);
      oA1 = __builtin_amdgcn_mfma_f32_32x32x16_bf16(vf[ks][1], paA, oA1, 0, 0, 0);
      oB0 = __builtin_amdgcn_mfma_f32_32x32x16_bf16(vf[ks][0], paB, oB0, 0, 0, 0);
      oB1 = __builtin_amdgcn_mfma_f32_32x32x16_bf16(vf[ks][1], paB, oB1, 0, 0, 0);
    }
    __builtin_amdgcn_s_setprio(0);
  }

  // ---- epilogue: store unnormalized partials. part[c][q][h][d], d = dh*32 + 8t + 4hi + j
  {
    int qA = q0 + l31, qB = qA + 32;
    bf16h* pA = part + ((size_t)(c * 4096 + qA) * 16 + h) * 64;
    bf16h* pB = part + ((size_t)(c * 4096 + qB) * 16 + h) * 64;
    #pragma unroll
    for (int dh = 0; dh < 2; ++dh) {
      const f32x16& aA = dh ? oA1 : oA0;
      const f32x16& aB = dh ? oB1 : oB0;
      #pragma unroll
      for (int t = 0; t < 4; ++t) {
        int d0 = dh * 32 + 8 * t + 4 * hi;
        ushort4 sa, sb;
        sa.x = bf16bits(aA[4 * t + 0]); sa.y = bf16bits(aA[4 * t + 1]);
        sa.z = bf16bits(aA[4 * t + 2]); sa.w = bf16bits(aA[4 * t + 3]);
        sb.x = bf16bits(aB[4 * t + 0]); sb.y = bf16bits(aB[4 * t + 1]);
        sb.z = bf16bits(aB[4 * t + 2]); sb.w = bf16bits(aB[4 * t + 3]);
        *reinterpret_cast<ushort4*>(pA + d0) = sa;
        *reinterpret_cast<ushort4*>(pB + d0) = sb;
      }
    }
    if (hi == 0) {
      lpart[(size_t)(c * 4096 + qA) * 16 + h] = lsumA;
      lpart[(size_t)(c * 4096 + qB) * 16 + h] = lsumB;
    }
  }
}

// ---------------- combine: ctx[q][h*64+d] = (P0+P1)/(l0+l1) ----------------
__global__ __launch_bounds__(256) void combine_part(const bf16h* __restrict__ part,
                                                    const float* __restrict__ lpart,
                                                    bf16h* __restrict__ ctx) {
  int idx = blockIdx.x * 256 + threadIdx.x;   // 65536 = 4096 q * 16 h
  int q = idx >> 4, h = idx & 15;
  const bf16h* p0 = part + ((size_t)q * 16 + h) * 64;
  const bf16h* p1 = p0 + (size_t)4096 * 1024;
  float inv = 1.0f / (lpart[(size_t)q * 16 + h] + lpart[(size_t)4096 * 16 + q * 16 + h]);
  bf16h* o = ctx + (size_t)q * 1024 + h * 64;
  #pragma unroll
  for (int w = 0; w < 8; ++w) {
    ushort4 a = *reinterpret_cast<const ushort4*>(p0 + w * 8);
    ushort4 b = *reinterpret_cast<const ushort4*>(p1 + w * 8);
    ushort4 c2 = *reinterpret_cast<const ushort4*>(p0 + w * 8 + 4);
    ushort4 d2 = *reinterpret_cast<const ushort4*>(p1 + w * 8 + 4);
    ushort4 r0, r1;
    r0.x = bf16bits((bf16tof(a.x) + bf16tof(b.x)) * inv);
    r0.y = bf16bits((bf16tof(a.y) + bf16tof(b.y)) * inv);
    r0.z = bf16bits((bf16tof(a.z) + bf16tof(b.z)) * inv);
    r0.w = bf16bits((bf16tof(a.w) + bf16tof(b.w)) * inv);
    r1.x = bf16bits((bf16tof(c2.x) + bf16tof(d2.x)) * inv);
    r1.y = bf16bits((bf16tof(c2.y) + bf16tof(d2.y)) * inv);
    r1.z = bf16bits((bf16tof(c2.z) + bf16tof(d2.z)) * inv);
    r1.w = bf16bits((bf16tof(c2.w) + bf16tof(d2.w)) * inv);
    *reinterpret_cast<ushort4*>(o + w * 8) = r0;
    *reinterpret_cast<ushort4*>(o + w * 8 + 4) = r1;
  }
}

extern "C" void kernel_launch(void* const* d_in, const int* in_sizes, int n_in,
                              void* d_out, int out_size, void* d_ws, size_t ws_size,
                              hipStream_t stream) {
  const float* hs = (const float*)d_in[0];
  const float* Wq = (const float*)d_in[1];
  const float* bq = (const float*)d_in[2];
  const float* Wk = (const float*)d_in[3];
  const float* bk = (const float*)d_in[4];
  const float* Wv = (const float*)d_in[5];
  const float* bv = (const float*)d_in[6];
  const float* Wo = (const float*)d_in[7];
  const float* bo = (const float*)d_in[8];
  float* out = (float*)d_out;

  const float QSCALE = 0.125f * 1.44269504088896f;  // 1/sqrt(64) * log2(e), folded into Wq/bq

  // workspace layout (35 MB, overlapping dead regions):
  //   [0,8M)   hb   (cast -> QKV gemm)      then part[0..8M)
  //   [8,12M)  WcT  (transpose -> QKV gemm) then part[8..12M)
  //   [12,16M) part tail, [16,16.5M) lpart  (attn -> combine)
  //   [17,29M) qk   (QKV gemm -> attn)      then ctx [17,25M) (combine -> O-proj)
  //   [29,33M) vtg  (QKV gemm -> attn)
  //   [33,35M) WoT, [35M) bcat
  char* ws = (char*)d_ws;
  const size_t MB = 1u << 20;
  bf16h* hb    = (bf16h*)(ws);
  bf16h* WcT   = (bf16h*)(ws + 8 * MB);
  bf16h* part  = (bf16h*)(ws);
  float* lpart = (float*)(ws + 16 * MB);
  bf16h* qk    = (bf16h*)(ws + 17 * MB);
  bf16h* ctx   = (bf16h*)(ws + 17 * MB);
  bf16h* vtg   = (bf16h*)(ws + 29 * MB);
  bf16h* WoT   = (bf16h*)(ws + 33 * MB);
  float* bcat  = (float*)(ws + 35 * MB);

  cast_f32_bf16<<<dim3(4096), dim3(256), 0, stream>>>(hs, hb, 4096 * 1024);
  transpose_cast_f32<<<dim3(32, 32), dim3(32, 8), 0, stream>>>(Wq, WcT, 1024, 1024, QSCALE);
  transpose_cast_f32<<<dim3(16, 32), dim3(32, 8), 0, stream>>>(Wk, WcT + 1024 * 1024, 1024, 512, 1.0f);
  transpose_cast_f32<<<dim3(16, 32), dim3(32, 8), 0, stream>>>(Wv, WcT + 1536 * 1024, 1024, 512, 1.0f);
  transpose_cast_f32<<<dim3(32, 32), dim3(32, 8), 0, stream>>>(Wo, WoT, 1024, 1024, 1.0f);
  concat_bias<<<dim3(8), dim3(256), 0, stream>>>(bq, bk, bv, bcat, QSCALE);
  // QKV projection: writes Q,K into qk (ld 1536) and V transposed into vtg
  gemm_bt<bf16h><<<dim3(16, 32), dim3(256), 0, stream>>>(hb, WcT, bcat, qk, 1536, vtg, 1536,
                                                         4096, 2048, 1024);
  attn_fwd<<<dim3(16, 16, 2), dim3(256), 0, stream>>>(qk, vtg, part, lpart);
  combine_part<<<dim3(256), dim3(256), 0, stream>>>(part, lpart, ctx);
  gemm_bt<float><<<dim3(8, 32), dim3(256), 0, stream>>>(ctx, WoT, bo, out, 1024, (bf16h*)nullptr,
                                                        0x40000000, 4096, 1024, 1024);
}

// Round 7
// 159.966 us; speedup vs baseline: 1.3118x; 1.3118x over previous
//
#include <hip/hip_runtime.h>
#include <hip/hip_bf16.h>
#include <cstdint>
#include <cstddef>

typedef __bf16 bf16x8 __attribute__((ext_vector_type(8)));
typedef float f32x4 __attribute__((ext_vector_type(4)));
typedef float f32x16 __attribute__((ext_vector_type(16)));
typedef uint32_t u32x4 __attribute__((ext_vector_type(4)));
typedef __hip_bfloat16 bf16h;

#define WAITVM(N) asm volatile("s_waitcnt vmcnt(" #N ")" ::: "memory")

__device__ __forceinline__ unsigned short bf16bits(float f) {
  bf16h h = __float2bfloat16(f);
  return __builtin_bit_cast(unsigned short, h);
}
__device__ __forceinline__ float bf16tof(unsigned short u) {
  union { uint32_t i; float f; } v; v.i = (uint32_t)u << 16; return v.f;
}

// ---------------- cast hidden fp32 -> bf16 ----------------
__global__ void cast_f32_bf16(const float* __restrict__ src, bf16h* __restrict__ dst, int n) {
  int i = (blockIdx.x * blockDim.x + threadIdx.x) * 4;
  if (i >= n) return;
  float4 v = *reinterpret_cast<const float4*>(src + i);
  ushort4 o;
  o.x = bf16bits(v.x); o.y = bf16bits(v.y); o.z = bf16bits(v.z); o.w = bf16bits(v.w);
  *reinterpret_cast<ushort4*>(dst + i) = o;
}

// ---------- transpose+cast+scale: src f32 [R][C] -> dst bf16 [C][R] ----------
__global__ void transpose_cast_f32(const float* __restrict__ src, bf16h* __restrict__ dst,
                                   int R, int C, float scale) {
  __shared__ float tile[32][33];
  int c0 = blockIdx.x * 32, r0 = blockIdx.y * 32;
  int tx = threadIdx.x, ty = threadIdx.y;
  #pragma unroll
  for (int i = 0; i < 32; i += 8)
    tile[ty + i][tx] = src[(size_t)(r0 + ty + i) * C + c0 + tx];
  __syncthreads();
  #pragma unroll
  for (int i = 0; i < 32; i += 8)
    dst[(size_t)(c0 + ty + i) * R + r0 + tx] = __float2bfloat16(tile[tx][ty + i] * scale);
}

__global__ void concat_bias(const float* __restrict__ bq, const float* __restrict__ bk,
                            const float* __restrict__ bv, float* __restrict__ bcat, float qscale) {
  int i = blockIdx.x * blockDim.x + threadIdx.x;
  if (i >= 2048) return;
  bcat[i] = (i < 1024) ? bq[i] * qscale : (i < 1536 ? bk[i - 1024] : bv[i - 1536]);
}

// ---------------- bf16 GEMM: C[M][N] = A[M][K] * BT[N][K]^T + bias ----------------
// Blocks with n0 >= vcol0 write TRANSPOSED into vtg[(col-vcol0)][row] (ld 4096) instead of C.
__device__ __forceinline__ void store_out(float* p, float v) { *p = v; }
__device__ __forceinline__ void store_out(bf16h* p, float v) { *p = __float2bfloat16(v); }

template <typename OutT>
__global__ __launch_bounds__(256) void gemm_bt(const bf16h* __restrict__ A, const bf16h* __restrict__ BT,
                                               const float* __restrict__ bias, OutT* __restrict__ C,
                                               int ldc, bf16h* __restrict__ vtg, int vcol0,
                                               int M, int N, int K) {
  __shared__ __align__(16) bf16h As[128 * 64];
  __shared__ __align__(16) bf16h Bs[128 * 64];
  const int tid = threadIdx.x;
  const int lane = tid & 63;
  const int m0 = blockIdx.y * 128, n0 = blockIdx.x * 128;
  const int wid = tid >> 6, wr = wid >> 1, wc = wid & 1;
  const int cl = lane & 15, rg = lane >> 4;
  const int srow = tid >> 3, scol = (tid & 7) * 8;
  f32x4 acc[4][4] = {};

  for (int k0 = 0; k0 < K; k0 += 64) {
    __syncthreads();
    #pragma unroll
    for (int i = 0; i < 4; ++i) {
      int r = i * 32 + srow;
      __builtin_amdgcn_global_load_lds(
          (__attribute__((address_space(1))) void*)(A + (size_t)(m0 + r) * K + k0 + scol),
          (__attribute__((address_space(3))) void*)(As + i * 2048 + tid * 8), 16, 0, 0);
    }
    #pragma unroll
    for (int i = 0; i < 4; ++i) {
      int r = i * 32 + srow;
      __builtin_amdgcn_global_load_lds(
          (__attribute__((address_space(1))) void*)(BT + (size_t)(n0 + r) * K + k0 + scol),
          (__attribute__((address_space(3))) void*)(Bs + i * 2048 + tid * 8), 16, 0, 0);
    }
    __syncthreads();
    #pragma unroll
    for (int ks = 0; ks < 2; ++ks) {
      bf16x8 af[4], bfr[4];
      #pragma unroll
      for (int mi = 0; mi < 4; ++mi)
        af[mi] = *reinterpret_cast<const bf16x8*>(As + (wr * 64 + mi * 16 + cl) * 64 + ks * 32 + rg * 8);
      #pragma unroll
      for (int ni = 0; ni < 4; ++ni)
        bfr[ni] = *reinterpret_cast<const bf16x8*>(Bs + (wc * 64 + ni * 16 + cl) * 64 + ks * 32 + rg * 8);
      #pragma unroll
      for (int mi = 0; mi < 4; ++mi)
        #pragma unroll
        for (int ni = 0; ni < 4; ++ni)
          acc[mi][ni] = __builtin_amdgcn_mfma_f32_16x16x32_bf16(af[mi], bfr[ni], acc[mi][ni], 0, 0, 0);
    }
  }
  if (n0 >= vcol0) {
    // transposed V^T store: vtg[col - vcol0][row], 4 consecutive rows per store
    #pragma unroll
    for (int ni = 0; ni < 4; ++ni) {
      int col = n0 + wc * 64 + ni * 16 + cl;
      float bv = bias[col];
      #pragma unroll
      for (int mi = 0; mi < 4; ++mi) {
        int row0 = m0 + wr * 64 + mi * 16 + rg * 4;
        ushort4 o;
        o.x = bf16bits(acc[mi][ni][0] + bv);
        o.y = bf16bits(acc[mi][ni][1] + bv);
        o.z = bf16bits(acc[mi][ni][2] + bv);
        o.w = bf16bits(acc[mi][ni][3] + bv);
        *reinterpret_cast<ushort4*>(vtg + (size_t)(col - vcol0) * 4096 + row0) = o;
      }
    }
  } else {
    #pragma unroll
    for (int ni = 0; ni < 4; ++ni) {
      int col = n0 + wc * 64 + ni * 16 + cl;
      float bv = bias[col];
      #pragma unroll
      for (int mi = 0; mi < 4; ++mi) {
        #pragma unroll
        for (int j = 0; j < 4; ++j) {
          int row = m0 + wr * 64 + mi * 16 + rg * 4 + j;
          store_out(&C[(size_t)row * ldc + col], acc[mi][ni][j] + bv);
        }
      }
    }
  }
}

// ---------------- flash attention: LDS-staged, counted-vmcnt pipeline (T3/T4) ----------------
// qk:  [4096][1536] bf16 (Q pre-scaled by 0.125*log2e at h*64 | K at 1024+g*64)
// vt:  [512][4096] bf16 (V^T)
// part:[2][4096][16][64] bf16 unnormalized O partials; lpart: [2][4096][16] f32 row-sums
// 4 waves/block, 64 q-rows/wave; KVBLK=64; blockIdx.z chunk = 2048 k's.
// 4 LDS buffers, staging depth 2, ONE s_barrier per tile, vmcnt never drained in the loop:
//   stage(t+2) -> s_waitcnt vmcnt(8) -> s_barrier -> compute(buf[t&3])
// own-vmcnt-then-barrier makes tile-t load completion collective across waves.
// Buffer reuse (distance 4 > depth 2): stage into buf[(t+2)&3] is issued after passing
// barrier(t-1), which implies all waves completed compute(t-2) on that buffer.
__global__ __launch_bounds__(256, 2) void attn_fwd(const bf16h* __restrict__ qk,
                                                   const bf16h* __restrict__ vt,
                                                   bf16h* __restrict__ part,
                                                   float* __restrict__ lpart) {
  __shared__ __align__(16) char smem[4 * 16384];  // 4 bufs x (K 8KB + Vt 8KB)
  const int tid = threadIdx.x, lane = tid & 63, wid = tid >> 6;
  const int l31 = lane & 31, hi = lane >> 5;
  const int h = blockIdx.y, g = h >> 1, c = blockIdx.z;
  const int q0 = blockIdx.x * 256 + wid * 64;   // frag A: q0..q0+31, frag B: q0+32..q0+63
  const int kbase = c * 2048;

  // Q fragments (B-operand of swapped QK)
  bf16x8 qfA[4], qfB[4];
  {
    const bf16h* qrowA = qk + (size_t)(q0 + l31) * 1536 + h * 64 + hi * 8;
    const bf16h* qrowB = qrowA + (size_t)32 * 1536;
    #pragma unroll
    for (int ds = 0; ds < 4; ++ds) {
      qfA[ds] = *reinterpret_cast<const bf16x8*>(qrowA + ds * 16);
      qfB[ds] = *reinterpret_cast<const bf16x8*>(qrowB + ds * 16);
    }
  }

  f32x16 oA0, oA1, oB0, oB1;
  #pragma unroll
  for (int i = 0; i < 16; ++i) { oA0[i] = 0.f; oA1[i] = 0.f; oB0[i] = 0.f; oB1[i] = 0.f; }
  float lsumA = 0.f, lsumB = 0.f;

  // stage K tile [64][64] and Vt tile [64][64]; inverse-swizzled SOURCE, linear LDS dest (m173)
  auto stage = [&](int kk, int b) {
    char* kb = smem + b * 16384;
    char* vb = kb + 8192;
    #pragma unroll
    for (int i = 0; i < 2; ++i) {
      int slot = tid + i * 256;            // 0..511 -> (r, s)
      int r = slot >> 3, s = slot & 7, sx = s ^ (r & 7);
      __builtin_amdgcn_global_load_lds(
          (__attribute__((address_space(1))) void*)(qk + (size_t)(kk + r) * 1536 + 1024 + g * 64 + sx * 8),
          (__attribute__((address_space(3))) void*)(kb + slot * 16), 16, 0, 0);
      __builtin_amdgcn_global_load_lds(
          (__attribute__((address_space(1))) void*)(vt + (size_t)(g * 64 + r) * 4096 + kk + sx * 8),
          (__attribute__((address_space(3))) void*)(vb + slot * 16), 16, 0, 0);
    }
  };

  // build P^T B-fragment from a k-slice of S (cvt_pk + permlane32_swap, T12)
  auto build_pa = [&](const f32x16& S, int u) -> bf16x8 {
    uint32_t w0, w1, w2, w3;
    asm("v_cvt_pk_bf16_f32 %0, %1, %2" : "=v"(w0) : "v"(S[8 * u + 0]), "v"(S[8 * u + 1]));
    asm("v_cvt_pk_bf16_f32 %0, %1, %2" : "=v"(w1) : "v"(S[8 * u + 2]), "v"(S[8 * u + 3]));
    asm("v_cvt_pk_bf16_f32 %0, %1, %2" : "=v"(w2) : "v"(S[8 * u + 4]), "v"(S[8 * u + 5]));
    asm("v_cvt_pk_bf16_f32 %0, %1, %2" : "=v"(w3) : "v"(S[8 * u + 6]), "v"(S[8 * u + 7]));
    asm("v_permlane32_swap_b32 %0, %1" : "+v"(w0), "+v"(w2));
    asm("v_permlane32_swap_b32 %0, %1" : "+v"(w1), "+v"(w3));
    u32x4 pw; pw[0] = w0; pw[1] = w1; pw[2] = w2; pw[3] = w3;
    return __builtin_bit_cast(bf16x8, pw);
  };

  // prologue: stage tiles 0 and 1
  stage(kbase, 0);
  stage(kbase + 64, 1);

  for (int tt = 0; tt < 32; ++tt) {
    if (tt + 2 < 32) stage(kbase + (tt + 2) * 64, (tt + 2) & 3);
    // wait for tile tt's 4 loads (leave in-flight tiles tt+1/tt+2 = 8/4 loads pending)
    if (tt < 30)      WAITVM(8);
    else if (tt == 30) WAITVM(4);
    else               WAITVM(0);
    __builtin_amdgcn_s_barrier();
    __builtin_amdgcn_sched_barrier(0);

    const char* kb = smem + (tt & 3) * 16384;
    const char* vb = kb + 8192;

    // ---- S^T = K * Q^T for both q-fragments (K reads shared)
    f32x16 sA0, sA1, sB0, sB1;
    #pragma unroll
    for (int i = 0; i < 16; ++i) { sA0[i] = 0.f; sA1[i] = 0.f; sB0[i] = 0.f; sB1[i] = 0.f; }
    __builtin_amdgcn_s_setprio(1);
    #pragma unroll
    for (int ds = 0; ds < 4; ++ds) {
      int cb = 32 * ds + 16 * hi;
      int r0 = l31, r1 = 32 + l31;
      bf16x8 k0 = *reinterpret_cast<const bf16x8*>(kb + ((r0 * 128 + cb) ^ ((r0 & 7) << 4)));
      bf16x8 k1 = *reinterpret_cast<const bf16x8*>(kb + ((r1 * 128 + cb) ^ ((r1 & 7) << 4)));
      sA0 = __builtin_amdgcn_mfma_f32_32x32x16_bf16(k0, qfA[ds], sA0, 0, 0, 0);
      sA1 = __builtin_amdgcn_mfma_f32_32x32x16_bf16(k1, qfA[ds], sA1, 0, 0, 0);
      sB0 = __builtin_amdgcn_mfma_f32_32x32x16_bf16(k0, qfB[ds], sB0, 0, 0, 0);
      sB1 = __builtin_amdgcn_mfma_f32_32x32x16_bf16(k1, qfB[ds], sB1, 0, 0, 0);
    }
    __builtin_amdgcn_s_setprio(0);

    // ---- P = exp2(S) (fixed max; Q pre-scaled) + row-sums via parallel accumulators
    float ra0 = 0.f, ra1 = 0.f, ra2 = 0.f, ra3 = 0.f;
    float rb0 = 0.f, rb1 = 0.f, rb2 = 0.f, rb3 = 0.f;
    #pragma unroll
    for (int r = 0; r < 16; r += 4) {
      #pragma unroll
      for (int j = 0; j < 4; ++j) {
        sA0[r + j] = __builtin_amdgcn_exp2f(sA0[r + j]);
        sA1[r + j] = __builtin_amdgcn_exp2f(sA1[r + j]);
        sB0[r + j] = __builtin_amdgcn_exp2f(sB0[r + j]);
        sB1[r + j] = __builtin_amdgcn_exp2f(sB1[r + j]);
      }
      ra0 += sA0[r] + sA0[r + 1]; ra1 += sA0[r + 2] + sA0[r + 3];
      ra2 += sA1[r] + sA1[r + 1]; ra3 += sA1[r + 2] + sA1[r + 3];
      rb0 += sB0[r] + sB0[r + 1]; rb1 += sB0[r + 2] + sB0[r + 3];
      rb2 += sB1[r] + sB1[r + 1]; rb3 += sB1[r + 2] + sB1[r + 3];
    }
    float rsA = (ra0 + ra1) + (ra2 + ra3);
    float rsB = (rb0 + rb1) + (rb2 + rb3);
    lsumA += rsA + __shfl_xor(rsA, 32);
    lsumB += rsB + __shfl_xor(rsB, 32);

    // ---- O^T += V^T P^T (V reads shared across fragments)
    __builtin_amdgcn_s_setprio(1);
    #pragma unroll
    for (int ks = 0; ks < 4; ++ks) {
      const int u = ks & 1;
      bf16x8 paA = build_pa(ks < 2 ? sA0 : sA1, u);
      bf16x8 paB = build_pa(ks < 2 ? sB0 : sB1, u);
      int cb = 32 * ks + 16 * hi;
      int r0 = l31, r1 = 32 + l31;
      bf16x8 vf0 = *reinterpret_cast<const bf16x8*>(vb + ((r0 * 128 + cb) ^ ((r0 & 7) << 4)));
      bf16x8 vf1 = *reinterpret_cast<const bf16x8*>(vb + ((r1 * 128 + cb) ^ ((r1 & 7) << 4)));
      oA0 = __builtin_amdgcn_mfma_f32_32x32x16_bf16(vf0, paA, oA0, 0, 0, 0);
      oA1 = __builtin_amdgcn_mfma_f32_32x32x16_bf16(vf1, paA, oA1, 0, 0, 0);
      oB0 = __builtin_amdgcn_mfma_f32_32x32x16_bf16(vf0, paB, oB0, 0, 0, 0);
      oB1 = __builtin_amdgcn_mfma_f32_32x32x16_bf16(vf1, paB, oB1, 0, 0, 0);
    }
    __builtin_amdgcn_s_setprio(0);
    __builtin_amdgcn_sched_barrier(0);
  }

  // ---- epilogue: store unnormalized partials. part[c][q][h][d], d = dh*32 + 8t + 4hi + j
  {
    int qA = q0 + l31, qB = qA + 32;
    bf16h* pA = part + ((size_t)(c * 4096 + qA) * 16 + h) * 64;
    bf16h* pB = part + ((size_t)(c * 4096 + qB) * 16 + h) * 64;
    #pragma unroll
    for (int dh = 0; dh < 2; ++dh) {
      const f32x16& aA = dh ? oA1 : oA0;
      const f32x16& aB = dh ? oB1 : oB0;
      #pragma unroll
      for (int t = 0; t < 4; ++t) {
        int d0 = dh * 32 + 8 * t + 4 * hi;
        ushort4 sa, sb;
        sa.x = bf16bits(aA[4 * t + 0]); sa.y = bf16bits(aA[4 * t + 1]);
        sa.z = bf16bits(aA[4 * t + 2]); sa.w = bf16bits(aA[4 * t + 3]);
        sb.x = bf16bits(aB[4 * t + 0]); sb.y = bf16bits(aB[4 * t + 1]);
        sb.z = bf16bits(aB[4 * t + 2]); sb.w = bf16bits(aB[4 * t + 3]);
        *reinterpret_cast<ushort4*>(pA + d0) = sa;
        *reinterpret_cast<ushort4*>(pB + d0) = sb;
      }
    }
    if (hi == 0) {
      lpart[(size_t)(c * 4096 + qA) * 16 + h] = lsumA;
      lpart[(size_t)(c * 4096 + qB) * 16 + h] = lsumB;
    }
  }
}

// ---------------- combine: ctx[q][h*64+d] = (P0+P1)/(l0+l1) ----------------
__global__ __launch_bounds__(256) void combine_part(const bf16h* __restrict__ part,
                                                    const float* __restrict__ lpart,
                                                    bf16h* __restrict__ ctx) {
  int idx = blockIdx.x * 256 + threadIdx.x;   // 65536 = 4096 q * 16 h
  int q = idx >> 4, h = idx & 15;
  const bf16h* p0 = part + ((size_t)q * 16 + h) * 64;
  const bf16h* p1 = p0 + (size_t)4096 * 1024;
  float inv = 1.0f / (lpart[(size_t)q * 16 + h] + lpart[(size_t)4096 * 16 + q * 16 + h]);
  bf16h* o = ctx + (size_t)q * 1024 + h * 64;
  #pragma unroll
  for (int w = 0; w < 8; ++w) {
    ushort4 a = *reinterpret_cast<const ushort4*>(p0 + w * 8);
    ushort4 b = *reinterpret_cast<const ushort4*>(p1 + w * 8);
    ushort4 c2 = *reinterpret_cast<const ushort4*>(p0 + w * 8 + 4);
    ushort4 d2 = *reinterpret_cast<const ushort4*>(p1 + w * 8 + 4);
    ushort4 r0, r1;
    r0.x = bf16bits((bf16tof(a.x) + bf16tof(b.x)) * inv);
    r0.y = bf16bits((bf16tof(a.y) + bf16tof(b.y)) * inv);
    r0.z = bf16bits((bf16tof(a.z) + bf16tof(b.z)) * inv);
    r0.w = bf16bits((bf16tof(a.w) + bf16tof(b.w)) * inv);
    r1.x = bf16bits((bf16tof(c2.x) + bf16tof(d2.x)) * inv);
    r1.y = bf16bits((bf16tof(c2.y) + bf16tof(d2.y)) * inv);
    r1.z = bf16bits((bf16tof(c2.z) + bf16tof(d2.z)) * inv);
    r1.w = bf16bits((bf16tof(c2.w) + bf16tof(d2.w)) * inv);
    *reinterpret_cast<ushort4*>(o + w * 8) = r0;
    *reinterpret_cast<ushort4*>(o + w * 8 + 4) = r1;
  }
}

extern "C" void kernel_launch(void* const* d_in, const int* in_sizes, int n_in,
                              void* d_out, int out_size, void* d_ws, size_t ws_size,
                              hipStream_t stream) {
  const float* hs = (const float*)d_in[0];
  const float* Wq = (const float*)d_in[1];
  const float* bq = (const float*)d_in[2];
  const float* Wk = (const float*)d_in[3];
  const float* bk = (const float*)d_in[4];
  const float* Wv = (const float*)d_in[5];
  const float* bv = (const float*)d_in[6];
  const float* Wo = (const float*)d_in[7];
  const float* bo = (const float*)d_in[8];
  float* out = (float*)d_out;

  const float QSCALE = 0.125f * 1.44269504088896f;  // 1/sqrt(64) * log2(e), folded into Wq/bq

  // workspace layout (35 MB, overlapping dead regions):
  //   [0,8M)   hb   (cast -> QKV gemm)      then part[0..8M)
  //   [8,12M)  WcT  (transpose -> QKV gemm) then part[8..12M)
  //   [12,16M) part tail, [16,16.5M) lpart  (attn -> combine)
  //   [17,29M) qk   (QKV gemm -> attn)      then ctx [17,25M) (combine -> O-proj)
  //   [29,33M) vtg  (QKV gemm -> attn)
  //   [33,35M) WoT, [35M) bcat
  char* ws = (char*)d_ws;
  const size_t MB = 1u << 20;
  bf16h* hb    = (bf16h*)(ws);
  bf16h* WcT   = (bf16h*)(ws + 8 * MB);
  bf16h* part  = (bf16h*)(ws);
  float* lpart = (float*)(ws + 16 * MB);
  bf16h* qk    = (bf16h*)(ws + 17 * MB);
  bf16h* ctx   = (bf16h*)(ws + 17 * MB);
  bf16h* vtg   = (bf16h*)(ws + 29 * MB);
  bf16h* WoT   = (bf16h*)(ws + 33 * MB);
  float* bcat  = (float*)(ws + 35 * MB);

  cast_f32_bf16<<<dim3(4096), dim3(256), 0, stream>>>(hs, hb, 4096 * 1024);
  transpose_cast_f32<<<dim3(32, 32), dim3(32, 8), 0, stream>>>(Wq, WcT, 1024, 1024, QSCALE);
  transpose_cast_f32<<<dim3(16, 32), dim3(32, 8), 0, stream>>>(Wk, WcT + 1024 * 1024, 1024, 512, 1.0f);
  transpose_cast_f32<<<dim3(16, 32), dim3(32, 8), 0, stream>>>(Wv, WcT + 1536 * 1024, 1024, 512, 1.0f);
  transpose_cast_f32<<<dim3(32, 32), dim3(32, 8), 0, stream>>>(Wo, WoT, 1024, 1024, 1.0f);
  concat_bias<<<dim3(8), dim3(256), 0, stream>>>(bq, bk, bv, bcat, QSCALE);
  // QKV projection: writes Q,K into qk (ld 1536) and V transposed into vtg
  gemm_bt<bf16h><<<dim3(16, 32), dim3(256), 0, stream>>>(hb, WcT, bcat, qk, 1536, vtg, 1536,
                                                         4096, 2048, 1024);
  attn_fwd<<<dim3(16, 16, 2), dim3(256), 0, stream>>>(qk, vtg, part, lpart);
  combine_part<<<dim3(256), dim3(256), 0, stream>>>(part, lpart, ctx);
  gemm_bt<float><<<dim3(8, 32), dim3(256), 0, stream>>>(ctx, WoT, bo, out, 1024, (bf16h*)nullptr,
                                                        0x40000000, 4096, 1024, 1024);
}

// Round 8
// 149.385 us; speedup vs baseline: 1.4047x; 1.0708x over previous
//
#include <hip/hip_runtime.h>
#include <hip/hip_bf16.h>
#include <cstdint>
#include <cstddef>

typedef __bf16 bf16x8 __attribute__((ext_vector_type(8)));
typedef float f32x4 __attribute__((ext_vector_type(4)));
typedef float f32x16 __attribute__((ext_vector_type(16)));
typedef uint32_t u32x4 __attribute__((ext_vector_type(4)));
typedef __hip_bfloat16 bf16h;

__device__ __forceinline__ unsigned short bf16bits(float f) {
  bf16h h = __float2bfloat16(f);
  return __builtin_bit_cast(unsigned short, h);
}
__device__ __forceinline__ float bf16tof(unsigned short u) {
  union { uint32_t i; float f; } v; v.i = (uint32_t)u << 16; return v.f;
}

// ---------------- cast hidden fp32 -> bf16 ----------------
__global__ void cast_f32_bf16(const float* __restrict__ src, bf16h* __restrict__ dst, int n) {
  int i = (blockIdx.x * blockDim.x + threadIdx.x) * 4;
  if (i >= n) return;
  float4 v = *reinterpret_cast<const float4*>(src + i);
  ushort4 o;
  o.x = bf16bits(v.x); o.y = bf16bits(v.y); o.z = bf16bits(v.z); o.w = bf16bits(v.w);
  *reinterpret_cast<ushort4*>(dst + i) = o;
}

// ---------------- fused weight prep: 4 transposes + bias concat in ONE launch ----------------
// blocks 0..1023: Wq->WcT (scaled); 1024..1535: Wk; 1536..2047: Wv; 2048..3071: Wo->WoT; 3072..3079: bias
__global__ __launch_bounds__(256) void prep_weights(const float* __restrict__ Wq, const float* __restrict__ Wk,
                                                    const float* __restrict__ Wv, const float* __restrict__ Wo,
                                                    const float* __restrict__ bq, const float* __restrict__ bk,
                                                    const float* __restrict__ bv,
                                                    bf16h* __restrict__ WcT, bf16h* __restrict__ WoT,
                                                    float* __restrict__ bcat, float qscale) {
  int b = blockIdx.x;
  int tx = threadIdx.x, ty = threadIdx.y;
  if (b >= 3072) {
    int i = (b - 3072) * 256 + ty * 32 + tx;
    bcat[i] = (i < 1024) ? bq[i] * qscale : (i < 1536 ? bk[i - 1024] : bv[i - 1536]);
    return;
  }
  const float* src; bf16h* dst; int C, bx, by; float sc = 1.0f;
  if (b < 1024)      { src = Wq; dst = WcT;               C = 1024; bx = b & 31;          by = b >> 5; sc = qscale; }
  else if (b < 1536) { src = Wk; dst = WcT + 1024 * 1024; C = 512;  bx = (b - 1024) & 15; by = (b - 1024) >> 4; }
  else if (b < 2048) { src = Wv; dst = WcT + 1536 * 1024; C = 512;  bx = (b - 1536) & 15; by = (b - 1536) >> 4; }
  else               { src = Wo; dst = WoT;               C = 1024; bx = (b - 2048) & 31; by = (b - 2048) >> 5; }
  __shared__ float tile[32][33];
  int c0 = bx * 32, r0 = by * 32;
  #pragma unroll
  for (int i = 0; i < 32; i += 8)
    tile[ty + i][tx] = src[(size_t)(r0 + ty + i) * C + c0 + tx];
  __syncthreads();
  #pragma unroll
  for (int i = 0; i < 32; i += 8)
    dst[(size_t)(c0 + ty + i) * 1024 + r0 + tx] = __float2bfloat16(tile[tx][ty + i] * sc);
}

// ---------------- QKV GEMM with fragment-permuted K/V epilogues ----------------
// A hb[4096][1024], BT WcT[2048][1024]. Outputs:
//   cols [0,1024):    qb[row][col] bf16 (row-major, Q pre-scaled via W/bias)
//   cols [1024,1536): kperm: flat = ((g*128+kt)*4+ds)*512 + (hi*32+kl)*8 + e
//                     (k=row: kt=k>>5, kl=k&31; d: ds=d>>4, hi=(d>>3)&1, e=d&7)
//   cols [1536,2048): vperm: flat = ((g*128+kt)*4+ks*2+dh)*512 + (hh*32+l31)*8 + e
//                     (k=row: kt=k>>5, ks=(k>>4)&1, hh=(k>>3)&1, e=k&7; d: l31=d&31, dh=d>>5)
// Each attn fragment read then becomes one lane-linear 1KB wave-coalesced chunk.
__global__ __launch_bounds__(256) void gemm_qkv(const bf16h* __restrict__ A, const bf16h* __restrict__ BT,
                                                const float* __restrict__ bias,
                                                bf16h* __restrict__ qb, bf16h* __restrict__ kperm,
                                                bf16h* __restrict__ vperm) {
  __shared__ __align__(16) bf16h As[128 * 64];
  __shared__ __align__(16) bf16h Bs[128 * 64];
  const int tid = threadIdx.x;
  const int lane = tid & 63;
  const int m0 = blockIdx.y * 128, n0 = blockIdx.x * 128;
  const int wid = tid >> 6, wr = wid >> 1, wc = wid & 1;
  const int cl = lane & 15, rg = lane >> 4;
  const int srow = tid >> 3, scol = (tid & 7) * 8;
  const int K = 1024;
  f32x4 acc[4][4] = {};

  for (int k0 = 0; k0 < K; k0 += 64) {
    __syncthreads();
    #pragma unroll
    for (int i = 0; i < 4; ++i) {
      int r = i * 32 + srow;
      __builtin_amdgcn_global_load_lds(
          (__attribute__((address_space(1))) void*)(A + (size_t)(m0 + r) * K + k0 + scol),
          (__attribute__((address_space(3))) void*)(As + i * 2048 + tid * 8), 16, 0, 0);
    }
    #pragma unroll
    for (int i = 0; i < 4; ++i) {
      int r = i * 32 + srow;
      __builtin_amdgcn_global_load_lds(
          (__attribute__((address_space(1))) void*)(BT + (size_t)(n0 + r) * K + k0 + scol),
          (__attribute__((address_space(3))) void*)(Bs + i * 2048 + tid * 8), 16, 0, 0);
    }
    __syncthreads();
    #pragma unroll
    for (int ks = 0; ks < 2; ++ks) {
      bf16x8 af[4], bfr[4];
      #pragma unroll
      for (int mi = 0; mi < 4; ++mi)
        af[mi] = *reinterpret_cast<const bf16x8*>(As + (wr * 64 + mi * 16 + cl) * 64 + ks * 32 + rg * 8);
      #pragma unroll
      for (int ni = 0; ni < 4; ++ni)
        bfr[ni] = *reinterpret_cast<const bf16x8*>(Bs + (wc * 64 + ni * 16 + cl) * 64 + ks * 32 + rg * 8);
      #pragma unroll
      for (int mi = 0; mi < 4; ++mi)
        #pragma unroll
        for (int ni = 0; ni < 4; ++ni)
          acc[mi][ni] = __builtin_amdgcn_mfma_f32_16x16x32_bf16(af[mi], bfr[ni], acc[mi][ni], 0, 0, 0);
    }
  }

  if (n0 < 1024) {          // ---- Q: row-major bf16
    #pragma unroll
    for (int ni = 0; ni < 4; ++ni) {
      int col = n0 + wc * 64 + ni * 16 + cl;
      float bv = bias[col];
      #pragma unroll
      for (int mi = 0; mi < 4; ++mi)
        #pragma unroll
        for (int j = 0; j < 4; ++j) {
          int row = m0 + wr * 64 + mi * 16 + rg * 4 + j;
          qb[(size_t)row * 1024 + col] = __float2bfloat16(acc[mi][ni][j] + bv);
        }
    }
  } else if (n0 < 1536) {   // ---- K permuted
    #pragma unroll
    for (int ni = 0; ni < 4; ++ni) {
      int col = n0 + wc * 64 + ni * 16 + cl;
      float bv = bias[col];
      int cd = col - 1024, gg = cd >> 6, d = cd & 63;
      int ds = d >> 4, hh = (d >> 3) & 1, e = d & 7;
      size_t cbase = (size_t)gg * 262144 + (size_t)ds * 512 + hh * 256 + e;
      #pragma unroll
      for (int mi = 0; mi < 4; ++mi) {
        int row0 = m0 + wr * 64 + mi * 16 + rg * 4;
        #pragma unroll
        for (int j = 0; j < 4; ++j) {
          int k = row0 + j;
          kperm[cbase + (size_t)(k >> 5) * 2048 + (k & 31) * 8] = __float2bfloat16(acc[mi][ni][j] + bv);
        }
      }
    }
  } else {                  // ---- V permuted (4 consecutive k -> ushort4)
    #pragma unroll
    for (int ni = 0; ni < 4; ++ni) {
      int col = n0 + wc * 64 + ni * 16 + cl;
      float bv = bias[col];
      int cd = col - 1536, gg = cd >> 6, d = cd & 63;
      int l31 = d & 31, dh = d >> 5;
      #pragma unroll
      for (int mi = 0; mi < 4; ++mi) {
        int row0 = m0 + wr * 64 + mi * 16 + rg * 4;
        int kt = row0 >> 5, ks = (row0 >> 4) & 1, hh = (row0 >> 3) & 1, e0 = row0 & 7;
        ushort4 o;
        o.x = bf16bits(acc[mi][ni][0] + bv);
        o.y = bf16bits(acc[mi][ni][1] + bv);
        o.z = bf16bits(acc[mi][ni][2] + bv);
        o.w = bf16bits(acc[mi][ni][3] + bv);
        *reinterpret_cast<ushort4*>(vperm + ((size_t)gg * 128 + kt) * 2048 +
                                    (size_t)(ks * 2 + dh) * 512 + (hh * 32 + l31) * 8 + e0) = o;
      }
    }
  }
}

// ---------------- O-projection GEMM (plain) ----------------
template <typename OutT>
__global__ __launch_bounds__(256) void gemm_bt(const bf16h* __restrict__ A, const bf16h* __restrict__ BT,
                                               const float* __restrict__ bias, OutT* __restrict__ C,
                                               int M, int N, int K) {
  __shared__ __align__(16) bf16h As[128 * 64];
  __shared__ __align__(16) bf16h Bs[128 * 64];
  const int tid = threadIdx.x;
  const int lane = tid & 63;
  const int m0 = blockIdx.y * 128, n0 = blockIdx.x * 128;
  const int wid = tid >> 6, wr = wid >> 1, wc = wid & 1;
  const int cl = lane & 15, rg = lane >> 4;
  const int srow = tid >> 3, scol = (tid & 7) * 8;
  f32x4 acc[4][4] = {};

  for (int k0 = 0; k0 < K; k0 += 64) {
    __syncthreads();
    #pragma unroll
    for (int i = 0; i < 4; ++i) {
      int r = i * 32 + srow;
      __builtin_amdgcn_global_load_lds(
          (__attribute__((address_space(1))) void*)(A + (size_t)(m0 + r) * K + k0 + scol),
          (__attribute__((address_space(3))) void*)(As + i * 2048 + tid * 8), 16, 0, 0);
    }
    #pragma unroll
    for (int i = 0; i < 4; ++i) {
      int r = i * 32 + srow;
      __builtin_amdgcn_global_load_lds(
          (__attribute__((address_space(1))) void*)(BT + (size_t)(n0 + r) * K + k0 + scol),
          (__attribute__((address_space(3))) void*)(Bs + i * 2048 + tid * 8), 16, 0, 0);
    }
    __syncthreads();
    #pragma unroll
    for (int ks = 0; ks < 2; ++ks) {
      bf16x8 af[4], bfr[4];
      #pragma unroll
      for (int mi = 0; mi < 4; ++mi)
        af[mi] = *reinterpret_cast<const bf16x8*>(As + (wr * 64 + mi * 16 + cl) * 64 + ks * 32 + rg * 8);
      #pragma unroll
      for (int ni = 0; ni < 4; ++ni)
        bfr[ni] = *reinterpret_cast<const bf16x8*>(Bs + (wc * 64 + ni * 16 + cl) * 64 + ks * 32 + rg * 8);
      #pragma unroll
      for (int mi = 0; mi < 4; ++mi)
        #pragma unroll
        for (int ni = 0; ni < 4; ++ni)
          acc[mi][ni] = __builtin_amdgcn_mfma_f32_16x16x32_bf16(af[mi], bfr[ni], acc[mi][ni], 0, 0, 0);
    }
  }
  #pragma unroll
  for (int ni = 0; ni < 4; ++ni) {
    int col = n0 + wc * 64 + ni * 16 + cl;
    float bv = bias[col];
    #pragma unroll
    for (int mi = 0; mi < 4; ++mi)
      #pragma unroll
      for (int j = 0; j < 4; ++j) {
        int row = m0 + wr * 64 + mi * 16 + rg * 4 + j;
        C[(size_t)row * N + col] = acc[mi][ni][j] + bv;
      }
  }
}

// ---------------- flash attention: 1-wave blocks, no LDS, no barriers, permuted-coalesced loads ----------------
// qb [4096][1024] bf16 (Q pre-scaled), kperm/vperm fragment-permuted (see gemm_qkv).
// part [2][4096][16][64] bf16, lpart [2][4096][16] f32.
// grid 2048 x 64thr: bid&7 = g (pins each kv-group to one XCD's L2); 64 q/wave; KVBLK=32; 64 tiles.
// Register double-buffer; compiler inserts waitcnts (pure reg loads).
__global__ __launch_bounds__(64, 2) void attn_fwd(const bf16h* __restrict__ qb,
                                                  const bf16h* __restrict__ kperm,
                                                  const bf16h* __restrict__ vperm,
                                                  bf16h* __restrict__ part,
                                                  float* __restrict__ lpart) {
  const int tid = threadIdx.x, l31 = tid & 31, hi = tid >> 5;
  const int bid = blockIdx.x;
  const int g = bid & 7;
  const int r2 = bid >> 3;
  const int qx = r2 & 63, hl = (r2 >> 6) & 1, c = r2 >> 7;
  const int h = g * 2 + hl;
  const int q0 = qx * 64;
  const int kt0 = c * 64;

  // Q fragments (B-operand of swapped QK)
  bf16x8 qfA[4], qfB[4];
  {
    const bf16h* qrA = qb + (size_t)(q0 + l31) * 1024 + h * 64 + hi * 8;
    #pragma unroll
    for (int ds = 0; ds < 4; ++ds) {
      qfA[ds] = *reinterpret_cast<const bf16x8*>(qrA + ds * 16);
      qfB[ds] = *reinterpret_cast<const bf16x8*>(qrA + (size_t)32 * 1024 + ds * 16);
    }
  }

  const bf16h* kg = kperm + ((size_t)g << 18) + tid * 8;
  const bf16h* vg = vperm + ((size_t)g << 18) + tid * 8;

  f32x16 oA0, oA1, oB0, oB1;
  #pragma unroll
  for (int i = 0; i < 16; ++i) { oA0[i] = 0.f; oA1[i] = 0.f; oB0[i] = 0.f; oB1[i] = 0.f; }
  float lsA = 0.f, lsB = 0.f;

  auto LOAD = [&](bf16x8 (&Kf)[4], bf16x8 (&Vf)[4], int kt) {
    const bf16h* kb = kg + (size_t)kt * 2048;
    const bf16h* vb = vg + (size_t)kt * 2048;
    #pragma unroll
    for (int s = 0; s < 4; ++s) {
      Kf[s] = *reinterpret_cast<const bf16x8*>(kb + s * 512);
      Vf[s] = *reinterpret_cast<const bf16x8*>(vb + s * 512);
    }
  };

  auto build_pa = [&](const f32x16& S, int u) -> bf16x8 {
    uint32_t w0, w1, w2, w3;
    asm("v_cvt_pk_bf16_f32 %0, %1, %2" : "=v"(w0) : "v"(S[8 * u + 0]), "v"(S[8 * u + 1]));
    asm("v_cvt_pk_bf16_f32 %0, %1, %2" : "=v"(w1) : "v"(S[8 * u + 2]), "v"(S[8 * u + 3]));
    asm("v_cvt_pk_bf16_f32 %0, %1, %2" : "=v"(w2) : "v"(S[8 * u + 4]), "v"(S[8 * u + 5]));
    asm("v_cvt_pk_bf16_f32 %0, %1, %2" : "=v"(w3) : "v"(S[8 * u + 6]), "v"(S[8 * u + 7]));
    asm("v_permlane32_swap_b32 %0, %1" : "+v"(w0), "+v"(w2));
    asm("v_permlane32_swap_b32 %0, %1" : "+v"(w1), "+v"(w3));
    u32x4 pw; pw[0] = w0; pw[1] = w1; pw[2] = w2; pw[3] = w3;
    return __builtin_bit_cast(bf16x8, pw);
  };

  auto BODY = [&](const bf16x8 (&Kf)[4], const bf16x8 (&Vf)[4]) {
    f32x16 sA, sB;
    #pragma unroll
    for (int i = 0; i < 16; ++i) { sA[i] = 0.f; sB[i] = 0.f; }
    __builtin_amdgcn_s_setprio(1);
    #pragma unroll
    for (int ds = 0; ds < 4; ++ds) {
      sA = __builtin_amdgcn_mfma_f32_32x32x16_bf16(Kf[ds], qfA[ds], sA, 0, 0, 0);
      sB = __builtin_amdgcn_mfma_f32_32x32x16_bf16(Kf[ds], qfB[ds], sB, 0, 0, 0);
    }
    __builtin_amdgcn_s_setprio(0);
    float ra0 = 0.f, ra1 = 0.f, rb0 = 0.f, rb1 = 0.f;
    #pragma unroll
    for (int r = 0; r < 16; r += 4) {
      #pragma unroll
      for (int j = 0; j < 4; ++j) {
        sA[r + j] = __builtin_amdgcn_exp2f(sA[r + j]);
        sB[r + j] = __builtin_amdgcn_exp2f(sB[r + j]);
      }
      ra0 += sA[r] + sA[r + 1]; ra1 += sA[r + 2] + sA[r + 3];
      rb0 += sB[r] + sB[r + 1]; rb1 += sB[r + 2] + sB[r + 3];
    }
    float rsA = ra0 + ra1, rsB = rb0 + rb1;
    lsA += rsA + __shfl_xor(rsA, 32);
    lsB += rsB + __shfl_xor(rsB, 32);
    __builtin_amdgcn_s_setprio(1);
    #pragma unroll
    for (int u = 0; u < 2; ++u) {
      bf16x8 paA = build_pa(sA, u);
      bf16x8 paB = build_pa(sB, u);
      oA0 = __builtin_amdgcn_mfma_f32_32x32x16_bf16(Vf[u * 2 + 0], paA, oA0, 0, 0, 0);
      oA1 = __builtin_amdgcn_mfma_f32_32x32x16_bf16(Vf[u * 2 + 1], paA, oA1, 0, 0, 0);
      oB0 = __builtin_amdgcn_mfma_f32_32x32x16_bf16(Vf[u * 2 + 0], paB, oB0, 0, 0, 0);
      oB1 = __builtin_amdgcn_mfma_f32_32x32x16_bf16(Vf[u * 2 + 1], paB, oB1, 0, 0, 0);
    }
    __builtin_amdgcn_s_setprio(0);
  };

  bf16x8 Ka[4], Va[4], Kb[4], Vb[4];
  LOAD(Ka, Va, kt0);
  for (int tt = 0; tt < 64; tt += 2) {
    int t1 = kt0 + tt + 1; if (t1 > 127) t1 = 127;
    LOAD(Kb, Vb, t1);
    BODY(Ka, Va);
    int t2 = kt0 + tt + 2; if (t2 > 127) t2 = 127;
    LOAD(Ka, Va, t2);
    BODY(Kb, Vb);
  }

  // epilogue: part[c][q][h][d], d = dh*32 + 8t + 4hi + j
  {
    int qA = q0 + l31, qB = qA + 32;
    bf16h* pA = part + ((size_t)(c * 4096 + qA) * 16 + h) * 64;
    bf16h* pB = part + ((size_t)(c * 4096 + qB) * 16 + h) * 64;
    #pragma unroll
    for (int dh = 0; dh < 2; ++dh) {
      const f32x16& aA = dh ? oA1 : oA0;
      const f32x16& aB = dh ? oB1 : oB0;
      #pragma unroll
      for (int t = 0; t < 4; ++t) {
        int d0 = dh * 32 + 8 * t + 4 * hi;
        ushort4 sa, sb;
        sa.x = bf16bits(aA[4 * t + 0]); sa.y = bf16bits(aA[4 * t + 1]);
        sa.z = bf16bits(aA[4 * t + 2]); sa.w = bf16bits(aA[4 * t + 3]);
        sb.x = bf16bits(aB[4 * t + 0]); sb.y = bf16bits(aB[4 * t + 1]);
        sb.z = bf16bits(aB[4 * t + 2]); sb.w = bf16bits(aB[4 * t + 3]);
        *reinterpret_cast<ushort4*>(pA + d0) = sa;
        *reinterpret_cast<ushort4*>(pB + d0) = sb;
      }
    }
    if (hi == 0) {
      lpart[(size_t)(c * 4096 + qA) * 16 + h] = lsA;
      lpart[(size_t)(c * 4096 + qB) * 16 + h] = lsB;
    }
  }
}

// ---------------- combine: ctx[q][h*64+d] = (P0+P1)/(l0+l1) ----------------
__global__ __launch_bounds__(256) void combine_part(const bf16h* __restrict__ part,
                                                    const float* __restrict__ lpart,
                                                    bf16h* __restrict__ ctx) {
  int idx = blockIdx.x * 256 + threadIdx.x;   // 65536 = 4096 q * 16 h
  int q = idx >> 4, h = idx & 15;
  const bf16h* p0 = part + ((size_t)q * 16 + h) * 64;
  const bf16h* p1 = p0 + (size_t)4096 * 1024;
  float inv = 1.0f / (lpart[(size_t)q * 16 + h] + lpart[(size_t)4096 * 16 + q * 16 + h]);
  bf16h* o = ctx + (size_t)q * 1024 + h * 64;
  #pragma unroll
  for (int w = 0; w < 8; ++w) {
    ushort4 a = *reinterpret_cast<const ushort4*>(p0 + w * 8);
    ushort4 b = *reinterpret_cast<const ushort4*>(p1 + w * 8);
    ushort4 c2 = *reinterpret_cast<const ushort4*>(p0 + w * 8 + 4);
    ushort4 d2 = *reinterpret_cast<const ushort4*>(p1 + w * 8 + 4);
    ushort4 r0, r1;
    r0.x = bf16bits((bf16tof(a.x) + bf16tof(b.x)) * inv);
    r0.y = bf16bits((bf16tof(a.y) + bf16tof(b.y)) * inv);
    r0.z = bf16bits((bf16tof(a.z) + bf16tof(b.z)) * inv);
    r0.w = bf16bits((bf16tof(a.w) + bf16tof(b.w)) * inv);
    r1.x = bf16bits((bf16tof(c2.x) + bf16tof(d2.x)) * inv);
    r1.y = bf16bits((bf16tof(c2.y) + bf16tof(d2.y)) * inv);
    r1.z = bf16bits((bf16tof(c2.z) + bf16tof(d2.z)) * inv);
    r1.w = bf16bits((bf16tof(c2.w) + bf16tof(d2.w)) * inv);
    *reinterpret_cast<ushort4*>(o + w * 8) = r0;
    *reinterpret_cast<ushort4*>(o + w * 8 + 4) = r1;
  }
}

extern "C" void kernel_launch(void* const* d_in, const int* in_sizes, int n_in,
                              void* d_out, int out_size, void* d_ws, size_t ws_size,
                              hipStream_t stream) {
  const float* hs = (const float*)d_in[0];
  const float* Wq = (const float*)d_in[1];
  const float* bq = (const float*)d_in[2];
  const float* Wk = (const float*)d_in[3];
  const float* bk = (const float*)d_in[4];
  const float* Wv = (const float*)d_in[5];
  const float* bv = (const float*)d_in[6];
  const float* Wo = (const float*)d_in[7];
  const float* bo = (const float*)d_in[8];
  float* out = (float*)d_out;

  const float QSCALE = 0.125f * 1.44269504088896f;  // 1/sqrt(64) * log2(e), folded into Wq/bq

  // workspace (35 MB):
  //   [0,8M)   hb (dies after gemm_qkv)   -> part [0,16M) overlays hb+WcT
  //   [8,12M)  WcT (dies after gemm_qkv)
  //   [16,16.5M) lpart
  //   [17,25M) qb (dies after attn)       -> ctx [17,25M) (combine out)
  //   [25,29M) kperm
  //   [29,33M) vperm
  //   [33,35M) WoT; [35M) bcat
  char* ws = (char*)d_ws;
  const size_t MB = 1u << 20;
  bf16h* hb    = (bf16h*)(ws);
  bf16h* WcT   = (bf16h*)(ws + 8 * MB);
  bf16h* part  = (bf16h*)(ws);
  float* lpart = (float*)(ws + 16 * MB);
  bf16h* qb    = (bf16h*)(ws + 17 * MB);
  bf16h* ctx   = (bf16h*)(ws + 17 * MB);
  bf16h* kperm = (bf16h*)(ws + 25 * MB);
  bf16h* vperm = (bf16h*)(ws + 29 * MB);
  bf16h* WoT   = (bf16h*)(ws + 33 * MB);
  float* bcat  = (float*)(ws + 35 * MB);

  cast_f32_bf16<<<dim3(4096), dim3(256), 0, stream>>>(hs, hb, 4096 * 1024);
  prep_weights<<<dim3(3080), dim3(32, 8), 0, stream>>>(Wq, Wk, Wv, Wo, bq, bk, bv,
                                                       WcT, WoT, bcat, QSCALE);
  gemm_qkv<<<dim3(16, 32), dim3(256), 0, stream>>>(hb, WcT, bcat, qb, kperm, vperm);
  attn_fwd<<<dim3(2048), dim3(64), 0, stream>>>(qb, kperm, vperm, part, lpart);
  combine_part<<<dim3(256), dim3(256), 0, stream>>>(part, lpart, ctx);
  gemm_bt<float><<<dim3(8, 32), dim3(256), 0, stream>>>(ctx, WoT, bo, out, 4096, 1024, 1024);
}